// Round 24
// baseline (322.300 us; speedup 1.0000x reference)
//
#include <hip/hip_runtime.h>
#include <hip/hip_bf16.h>

// B=8, S=2048, D=1024, fp32 in/out.
static constexpr int S = 2048;
static constexpr int D = 1024;
static constexpr int NB = 8;

#define LOG2E 1.4426950408889634f

typedef float    f32x4  __attribute__((ext_vector_type(4)));
typedef _Float16 f16x4  __attribute__((ext_vector_type(4)));
typedef _Float16 f16x8  __attribute__((ext_vector_type(8)));

#define CM_F32    0
#define CM_TRANSV 2
#define CM_F16    3

#define GLD16(g, l) __builtin_amdgcn_global_load_lds(                         \
    (const __attribute__((address_space(1))) void*)(g),                       \
    (__attribute__((address_space(3))) void*)(l), 16, 0, 0)

#define MFMA16(a, b, c) __builtin_amdgcn_mfma_f32_16x16x32_f16((a), (b), (c), 0, 0, 0)
#define BAR() __builtin_amdgcn_s_barrier()
#define PRIO1() __builtin_amdgcn_s_setprio(1)
#define PRIO0() __builtin_amdgcn_s_setprio(0)
#define WAIT_LGKM(n) asm volatile("s_waitcnt lgkmcnt(" #n ")" ::: "memory")
#define WAIT_VM(n)   asm volatile("s_waitcnt vmcnt(" #n ")" ::: "memory")

// ---------------------------------------------------------------------------
// fp16 1-term GEMM (C = A*B^T), 256xBNT tile, 8 waves.
//   BK=64, BNT=256 (PV + Q/K proj): r23 FINE 4-phase loop (verified best):
//     16-MFMA phases, reads one phase ahead, lgkm 4/8/4/8, vm(4)@F1/F3,
//     2 barriers/tile. 128 KB LDS, 1 block/CU.
//   BK=32, BNT=256 (scores, r24): single-plane K-tile, 64 KB LDS ->
//     2 blocks/CU (grid 512 = 2x256). Mechanism: co-resident blocks have
//     independent barrier rhythms -> HW overlaps one block's seal stall with
//     the other's MFMA (m114). Per tile: stage(t+1)[4]; vm(4); BAR; 12 reads;
//     lgkm(4); 16 MFMA; lgkm(0); 16 MFMA; BAR. Accumulation order bit-
//     identical to BK64 (same k sequence).
//   BK=64, BNT=128 (TRANSV V-proj): r19 2-phase loop verbatim.
// LDS planes [rows][64B], 4-slot XOR swizzle (slot = chunk ^ ((row>>1)&3)),
// both sides, 0-conflict (r10-verified). XCD-bijective block swizzle (m204).
// Epilogues: CM_F32/CM_F16 scalar; CM_TRANSV LDS-transposed coalesced.
// ---------------------------------------------------------------------------
template <int CMODE, int BNT, int BK>
__global__ __launch_bounds__(512, 1) void bgemm256(
    const _Float16* __restrict__ Ah_, long sAz,
    const _Float16* __restrict__ Bh_, long sBz,
    int lda, int ldb,
    void* __restrict__ C1, int ldc, long sCz,
    const float* __restrict__ bias, int K)
{
    extern __shared__ char smem[];
    constexpr int NW_N  = BNT / 64;          // 4 or 2
    constexpr int NW_M  = 8 / NW_N;          // 2 or 4
    constexpr int WM    = 256 / NW_M;        // 128 or 64
    constexpr int MI    = WM / 16;           // 8 or 4
    constexpr int NPL   = BK / 32;           // planes per tile (2 or 1)
    constexpr int APLANE = 16384;            // 256 rows x 64 B
    constexpr int BPLANE = BNT * 64;         // 16 KB or 8 KB
    constexpr int BOFF   = NPL * APLANE;
    constexpr int BUFSZ  = NPL * (APLANE + BPLANE);

    // ---- XCD-aware bijective block swizzle (T1, m204) ----
    int bx, by, bz;
    {
        const int gx = gridDim.x, gy = gridDim.y;
        const int nwg = gx * gy * gridDim.z;
        const int wg = blockIdx.x + gx * (blockIdx.y + gy * blockIdx.z);
        const int q = nwg >> 3, r = nwg & 7;
        const int xcd = wg & 7, i = wg >> 3;
        const int nid = (xcd < r) ? xcd * (q + 1) + i
                                  : r * (q + 1) + (xcd - r) * q + i;
        bx = nid % gx;
        const int tmp = nid / gx;
        by = tmp % gy;
        bz = tmp / gy;
    }

    const int t = threadIdx.x;
    const int z = bz;
    const int m0 = by * 256;
    const int n0 = bx * BNT;
    const int lane = t & 63, wid = t >> 6;
    const int wr = wid / NW_N, wc = wid % NW_N;
    const int fr = lane & 15, fq = lane >> 4;
    const int lrow = lane >> 2, lslot = lane & 3;

    const _Float16* Ahz = Ah_ + (long)z * sAz;
    const _Float16* Bhz = Bh_ + (long)z * sBz;

    auto stA = [&](int tile, int p) {
        char* lbase = smem + (tile & 1) * BUFSZ + p * APLANE;
#pragma unroll
        for (int i = 0; i < 2; ++i) {
            const int row = wid * 32 + i * 16 + lrow;
            const int chunk = lslot ^ ((row >> 1) & 3);
            const long kk = (long)tile * BK + p * 32 + chunk * 8;
            GLD16(Ahz + (long)(m0 + row) * lda + kk,
                  lbase + (wid * 32 + i * 16) * 64);
        }
    };
    auto stB = [&](int tile, int p) {
        char* lbase = smem + (tile & 1) * BUFSZ + BOFF + p * BPLANE;
        if constexpr (BNT == 256) {
#pragma unroll
            for (int i = 0; i < 2; ++i) {
                const int row = wid * 32 + i * 16 + lrow;
                const int chunk = lslot ^ ((row >> 1) & 3);
                const long kk = (long)tile * BK + p * 32 + chunk * 8;
                GLD16(Bhz + (long)(n0 + row) * ldb + kk,
                      lbase + (wid * 32 + i * 16) * 64);
            }
        } else {
            const int row = wid * 16 + lrow;
            const int chunk = lslot ^ ((row >> 1) & 3);
            const long kk = (long)tile * BK + p * 32 + chunk * 8;
            GLD16(Bhz + (long)(n0 + row) * ldb + kk, lbase + (wid * 16) * 64);
        }
    };
    auto rdA = [&](int buf, int p, int mi) -> f16x8 {
        const int row = wr * WM + mi * 16 + fr;
        const int slot = fq ^ ((row >> 1) & 3);
        return *(const f16x8*)(smem + buf * BUFSZ + p * APLANE +
                               row * 64 + slot * 16);
    };
    auto rdB = [&](int buf, int p, int ni) -> f16x8 {
        const int row = wc * 64 + ni * 16 + fr;
        const int slot = fq ^ ((row >> 1) & 3);
        return *(const f16x8*)(smem + buf * BUFSZ + BOFF + p * BPLANE +
                               row * 64 + slot * 16);
    };

    f32x4 acc[MI][4] = {};
    const int ktiles = K / BK;

    if constexpr (BK == 32) {
        // ---- r24: single-plane BK32, 64 KB LDS, 2 blocks/CU (MI == 8) ----
        f16x8 b[4], a[8];
        stA(0, 0); stB(0, 0);
        WAIT_VM(0);
        BAR();

        for (int tt = 0; tt < ktiles; ++tt) {
            const int buf = tt & 1;
            const bool pf = (tt + 1 < ktiles);
            if (pf) { stA(tt + 1, 0); stB(tt + 1, 0); WAIT_VM(4); }
            else    { WAIT_VM(0); }
            BAR();
#pragma unroll
            for (int ni = 0; ni < 4; ++ni) b[ni] = rdB(buf, 0, ni);
#pragma unroll
            for (int mi = 0; mi < 8; ++mi) a[mi] = rdA(buf, 0, mi);
            WAIT_LGKM(4);                  // b[0-3], a[0-3] landed
            PRIO1();
#pragma unroll
            for (int mi = 0; mi < 4; ++mi)
#pragma unroll
                for (int ni = 0; ni < 4; ++ni)
                    acc[mi][ni] = MFMA16(a[mi], b[ni], acc[mi][ni]);
            PRIO0();
            WAIT_LGKM(0);                  // a[4-7] landed
            PRIO1();
#pragma unroll
            for (int mi = 0; mi < 4; ++mi)
#pragma unroll
                for (int ni = 0; ni < 4; ++ni)
                    acc[4 + mi][ni] = MFMA16(a[4 + mi], b[ni], acc[4 + mi][ni]);
            PRIO0();
            BAR();                         // reads drained; next restage safe
        }
    } else if constexpr (BNT == 256) {
        // ---- r23 fine 4-phase loop (verified best), MI == 8 ----
        f16x8 b0[4], b1[4], a0[8], a1[8];
        stA(0, 0); stB(0, 0); stA(0, 1); stB(0, 1);
        WAIT_VM(0);
        BAR();
#pragma unroll
        for (int ni = 0; ni < 4; ++ni) b0[ni] = rdB(0, 0, ni);
#pragma unroll
        for (int mi = 0; mi < 4; ++mi) a0[mi] = rdA(0, 0, mi);

        for (int tt = 0; tt < ktiles; ++tt) {
            const int buf = tt & 1;
            const bool pf = (tt + 1 < ktiles);
            // F0
            if (pf) stA(tt + 1, 0);
#pragma unroll
            for (int mi = 0; mi < 4; ++mi) a0[4 + mi] = rdA(buf, 0, 4 + mi);
            WAIT_LGKM(4);
            PRIO1();
#pragma unroll
            for (int mi = 0; mi < 4; ++mi)
#pragma unroll
                for (int ni = 0; ni < 4; ++ni)
                    acc[mi][ni] = MFMA16(a0[mi], b0[ni], acc[mi][ni]);
            PRIO0();
            // F1
            if (pf) { stB(tt + 1, 0); WAIT_VM(4); }
            else    { WAIT_VM(0); }
            BAR();
#pragma unroll
            for (int ni = 0; ni < 4; ++ni) b1[ni] = rdB(buf, 1, ni);
#pragma unroll
            for (int mi = 0; mi < 4; ++mi) a1[mi] = rdA(buf, 1, mi);
            WAIT_LGKM(8);
            PRIO1();
#pragma unroll
            for (int mi = 0; mi < 4; ++mi)
#pragma unroll
                for (int ni = 0; ni < 4; ++ni)
                    acc[4 + mi][ni] = MFMA16(a0[4 + mi], b0[ni], acc[4 + mi][ni]);
            PRIO0();
            // F2
            if (pf) stA(tt + 1, 1);
#pragma unroll
            for (int mi = 0; mi < 4; ++mi) a1[4 + mi] = rdA(buf, 1, 4 + mi);
            WAIT_LGKM(4);
            PRIO1();
#pragma unroll
            for (int mi = 0; mi < 4; ++mi)
#pragma unroll
                for (int ni = 0; ni < 4; ++ni)
                    acc[mi][ni] = MFMA16(a1[mi], b1[ni], acc[mi][ni]);
            PRIO0();
            // F3
            if (pf) { stB(tt + 1, 1); WAIT_VM(4); }
            else    { WAIT_VM(0); }
            BAR();
            if (pf) {
                const int nb = buf ^ 1;
#pragma unroll
                for (int ni = 0; ni < 4; ++ni) b0[ni] = rdB(nb, 0, ni);
#pragma unroll
                for (int mi = 0; mi < 4; ++mi) a0[mi] = rdA(nb, 0, mi);
                WAIT_LGKM(8);
            } else {
                WAIT_LGKM(0);
            }
            PRIO1();
#pragma unroll
            for (int mi = 0; mi < 4; ++mi)
#pragma unroll
                for (int ni = 0; ni < 4; ++ni)
                    acc[4 + mi][ni] = MFMA16(a1[4 + mi], b1[ni], acc[4 + mi][ni]);
            PRIO0();
        }
    } else {
        // ---- BNT=128, BK=64: r19 2-phase loop verbatim (verified) ----
        f16x8 b0[4], b1[4], a0[MI], a1[MI];
        auto mb = [&](f16x8 (&A)[MI], f16x8 (&B)[4]) {
#pragma unroll
            for (int mi = 0; mi < MI; ++mi)
#pragma unroll
                for (int ni = 0; ni < 4; ++ni)
                    acc[mi][ni] = MFMA16(A[mi], B[ni], acc[mi][ni]);
        };
        stA(0, 0); stB(0, 0); stA(0, 1); stB(0, 1);
        WAIT_VM(0);
        BAR();
#pragma unroll
        for (int ni = 0; ni < 4; ++ni) b0[ni] = rdB(0, 0, ni);
#pragma unroll
        for (int mi = 0; mi < MI; ++mi) a0[mi] = rdA(0, 0, mi);

        for (int tt = 0; tt < ktiles; ++tt) {
            const int buf = tt & 1;
            const bool pf = (tt + 1 < ktiles);
            if (pf) { stA(tt + 1, 0); stB(tt + 1, 0); WAIT_VM(3); }
            else    { WAIT_VM(0); }
            BAR();
#pragma unroll
            for (int ni = 0; ni < 4; ++ni) b1[ni] = rdB(buf, 1, ni);
#pragma unroll
            for (int mi = 0; mi < MI; ++mi) a1[mi] = rdA(buf, 1, mi);
            WAIT_LGKM(8);
            PRIO1(); mb(a0, b0); PRIO0();
            BAR();
            if (pf) { stA(tt + 1, 1); stB(tt + 1, 1); WAIT_VM(3); }
            WAIT_LGKM(0);
            BAR();
            PRIO1(); mb(a1, b1); PRIO0();
            if (pf) {
                const int nb = buf ^ 1;
#pragma unroll
                for (int ni = 0; ni < 4; ++ni) b0[ni] = rdB(nb, 0, ni);
#pragma unroll
                for (int mi = 0; mi < MI; ++mi) a0[mi] = rdA(nb, 0, mi);
            }
        }
    }

    // ---------------- epilogue ----------------
    if constexpr (CMODE == CM_TRANSV) {
        // BNT=128 only. LDS transpose: Tt[128 d][272 f16] (544-B stride).
        constexpr int LDT = 544;
#pragma unroll
        for (int mi = 0; mi < MI; ++mi) {
            const int row0 = wr * WM + mi * 16 + fq * 4;   // 0..255, mult of 4
#pragma unroll
            for (int ni = 0; ni < 4; ++ni) {
                const int colp = wc * 64 + ni * 16 + fr;    // 0..127
                const float bv = bias[n0 + colp];
                f16x4 h;
#pragma unroll
                for (int j = 0; j < 4; ++j) h[j] = (_Float16)(acc[mi][ni][j] + bv);
                *(f16x4*)(smem + colp * LDT + row0 * 2) = h;
            }
        }
        BAR();
        const int b_ = m0 >> 11;
        const int sbase = m0 & (S - 1);
        const int l31 = lane & 31, lh = lane >> 5;
        _Float16* Vp = (_Float16*)C1;
#pragma unroll
        for (int it = 0; it < 8; ++it) {
            const int dd = wid * 16 + it * 2 + lh;
            const f16x8 v = *(const f16x8*)(smem + dd * LDT + l31 * 16);
            *(f16x8*)(Vp + ((long)(b_ * D + n0 + dd)) * S + sbase + l31 * 8) = v;
        }
    } else {
#pragma unroll
        for (int mi = 0; mi < MI; ++mi) {
            const int rbase = m0 + wr * WM + mi * 16 + fq * 4;
#pragma unroll
            for (int ni = 0; ni < 4; ++ni) {
                const int col = n0 + wc * 64 + ni * 16 + fr;
                f32x4 a = acc[mi][ni];
                if (CMODE != CM_F32) {
                    const float bv = bias[col];
#pragma unroll
                    for (int j = 0; j < 4; ++j) a[j] += bv;
                }
                if (CMODE == CM_F32) {
                    float* C = (float*)C1 + (long)z * sCz;
#pragma unroll
                    for (int j = 0; j < 4; ++j)
                        C[(long)(rbase + j) * ldc + col] = a[j];
                } else {  // CM_F16
                    _Float16* Ch = (_Float16*)C1;
#pragma unroll
                    for (int j = 0; j < 4; ++j)
                        Ch[(long)(rbase + j) * ldc + col] = (_Float16)a[j];
                }
            }
        }
    }
}

// ---------------------------------------------------------------------------
// X -> single fp16 plane.
__global__ __launch_bounds__(256) void xsplit(
    const float* __restrict__ X, _Float16* __restrict__ Xh)
{
    const long i = ((long)blockIdx.x * 256 + threadIdx.x) * 8;
    f32x4 v0 = *(const f32x4*)(X + i);
    f32x4 v1 = *(const f32x4*)(X + i + 4);
    f16x8 h;
#pragma unroll
    for (int j = 0; j < 4; ++j) { h[j] = (_Float16)v0[j]; h[4 + j] = (_Float16)v1[j]; }
    *(f16x8*)(Xh + i) = h;
}

// ---------------------------------------------------------------------------
// Transpose 1024x1024 W -> single f16 plane (1-term projections).
__global__ void wsplit(const float* __restrict__ W0, const float* __restrict__ W1,
                       const float* __restrict__ W2, _Float16* __restrict__ Th)
{
    const float* W = blockIdx.z == 0 ? W0 : (blockIdx.z == 1 ? W1 : W2);
    _Float16* th = Th + (long)blockIdx.z * 1024 * 1024;
    __shared__ float tile[32][33];
    const int bx = blockIdx.x * 32, by = blockIdx.y * 32;
    const int tx = threadIdx.x, ty = threadIdx.y;
#pragma unroll
    for (int i = ty; i < 32; i += 8) tile[i][tx] = W[(long)(by + i) * 1024 + bx + tx];
    __syncthreads();
#pragma unroll
    for (int i = ty; i < 32; i += 8)
        th[(long)(bx + i) * 1024 + by + tx] = (_Float16)tile[tx][i];
}

// ---------------------------------------------------------------------------
// Fused row softmax: f32 score row -> P = exp(s-m)/l as fp16, in-place.
__global__ __launch_bounds__(256) void pconv(float* __restrict__ Sb)
{
    const long row = blockIdx.x;
    float* p = Sb + row * (long)S;
    const int t = threadIdx.x;

    f32x4 x0 = *(const f32x4*)(p + t * 8);
    f32x4 x1 = *(const f32x4*)(p + t * 8 + 4);

    float m = -3.4e38f;
#pragma unroll
    for (int j = 0; j < 4; ++j) m = fmaxf(m, fmaxf(x0[j], x1[j]));
#pragma unroll
    for (int o = 32; o >= 1; o >>= 1) m = fmaxf(m, __shfl_xor(m, o));

    __shared__ float wm[4], wsum[4];
    const int wid = t >> 6, lane = t & 63;
    if (lane == 0) wm[wid] = m;
    __syncthreads();
    m = fmaxf(fmaxf(wm[0], wm[1]), fmaxf(wm[2], wm[3]));

    float e[8], ssum = 0.f;
#pragma unroll
    for (int j = 0; j < 4; ++j) {
        e[j]     = exp2f((x0[j] - m) * LOG2E);
        e[4 + j] = exp2f((x1[j] - m) * LOG2E);
        ssum += e[j] + e[4 + j];
    }
#pragma unroll
    for (int o = 32; o >= 1; o >>= 1) ssum += __shfl_xor(ssum, o);
    if (lane == 0) wsum[wid] = ssum;
    __syncthreads();
    const float invl = 1.0f / (wsum[0] + wsum[1] + wsum[2] + wsum[3]);

    f16x8 outv;
#pragma unroll
    for (int j = 0; j < 8; ++j) outv[j] = (_Float16)(e[j] * invl);
    *(f16x8*)((_Float16*)p + t * 8) = outv;
}

// ---------------------------------------------------------------------------
extern "C" void kernel_launch(void* const* d_in, const int* in_sizes, int n_in,
                              void* d_out, int out_size, void* d_ws, size_t ws_size,
                              hipStream_t stream)
{
    const float* X  = (const float*)d_in[0];
    const float* Wq = (const float*)d_in[1];
    const float* bq = (const float*)d_in[2];
    const float* Wk = (const float*)d_in[3];
    const float* bk = (const float*)d_in[4];
    const float* Wv = (const float*)d_in[5];
    const float* bv = (const float*)d_in[6];
    float* out = (float*)d_out;
    char* ws = (char*)d_ws;
    const size_t MB = 1u << 20;

    // layout (230 MB): [0,6) Wh[3] f16  [6,38) Qh f16  [38,70) Kh f16
    // [70,102) Vt f16  [102,230) Sb f32 [8][S][S] (P f16 in-place)
    // Xh (32 MB f16) aliases Sb's first part [102,134) — dead before scores.
    _Float16* Wh = (_Float16*)ws;
    _Float16* Qh = (_Float16*)(ws + 6 * MB);
    _Float16* Kh = (_Float16*)(ws + 38 * MB);
    _Float16* Vt = (_Float16*)(ws + 70 * MB);
    float*    Sb = (float*)(ws + 102 * MB);
    _Float16* Xh = (_Float16*)(ws + 102 * MB);

    const int LDS_256_64 = 131072;  // BK64 BNT256: 2 bufs x 64 KB
    const int LDS_256_32 = 65536;   // BK32 BNT256: 2 bufs x 32 KB (2 blocks/CU)
    const int LDS_128_64 = 98304;   // BK64 BNT128
    (void)hipFuncSetAttribute(reinterpret_cast<const void*>(&bgemm256<CM_F16, 256, 64>),
                        hipFuncAttributeMaxDynamicSharedMemorySize, LDS_256_64);
    (void)hipFuncSetAttribute(reinterpret_cast<const void*>(&bgemm256<CM_F32, 256, 64>),
                        hipFuncAttributeMaxDynamicSharedMemorySize, LDS_256_64);
    (void)hipFuncSetAttribute(reinterpret_cast<const void*>(&bgemm256<CM_F32, 256, 32>),
                        hipFuncAttributeMaxDynamicSharedMemorySize, LDS_256_32);
    (void)hipFuncSetAttribute(reinterpret_cast<const void*>(&bgemm256<CM_TRANSV, 128, 64>),
                        hipFuncAttributeMaxDynamicSharedMemorySize, LDS_128_64);

    // 1) convert X -> f16 single plane; W -> f16 single plane (transposed)
    xsplit<<<dim3(8192), 256, 0, stream>>>(X, Xh);
    wsplit<<<dim3(32, 32, 3), dim3(32, 8), 0, stream>>>(Wq, Wk, Wv, Wh);

    // 2) projections: 1-term fp16 (Xh * Wh); Q,K single f16; V -> Vt f16.
    const long MW = 1024 * 1024;
    bgemm256<CM_F16, 256, 64><<<dim3(D / 256, 64, 1), 512, LDS_256_64, stream>>>(
        Xh, 0, Wh, 0, D, D, Qh, D, 0, bq, D);
    bgemm256<CM_F16, 256, 64><<<dim3(D / 256, 64, 1), 512, LDS_256_64, stream>>>(
        Xh, 0, Wh + MW, 0, D, D, Kh, D, 0, bk, D);
    bgemm256<CM_TRANSV, 128, 64><<<dim3(D / 128, 64, 1), 512, LDS_128_64, stream>>>(
        Xh, 0, Wh + 2 * MW, 0, D, D, Vt, 0, 0, bv, D);

    // 3) single pass, all 8 batches: scores (BK32, 2 blocks/CU) -> softmax -> PV
    bgemm256<CM_F32, 256, 32><<<dim3(S / 256, S / 256, NB), 512, LDS_256_32, stream>>>(
        Qh, (long)S * D, Kh, (long)S * D,
        D, D, Sb, S, (long)S * S, nullptr, D);
    pconv<<<dim3(NB * S), 256, 0, stream>>>(Sb);
    // PV: A = f16 P rows embedded in f32 buffer (lda = 2S f16 elements)
    bgemm256<CM_F32, 256, 64><<<dim3(D / 256, S / 256, NB), 512, LDS_256_64, stream>>>(
        (const _Float16*)Sb, 2L * S * S, Vt, (long)D * S,
        2 * S, S, out, D, (long)S * D, nullptr, S);
}

// Round 25
// 319.340 us; speedup vs baseline: 1.0093x; 1.0093x over previous
//
#include <hip/hip_runtime.h>
#include <hip/hip_bf16.h>

// B=8, S=2048, D=1024, fp32 in/out.
static constexpr int S = 2048;
static constexpr int D = 1024;
static constexpr int NB = 8;

#define LOG2E 1.4426950408889634f

typedef float    f32x4  __attribute__((ext_vector_type(4)));
typedef _Float16 f16x4  __attribute__((ext_vector_type(4)));
typedef _Float16 f16x8  __attribute__((ext_vector_type(8)));

#define CM_F32    0
#define CM_TRANSV 2
#define CM_F16    3

#define GLD16(g, l) __builtin_amdgcn_global_load_lds(                         \
    (const __attribute__((address_space(1))) void*)(g),                       \
    (__attribute__((address_space(3))) void*)(l), 16, 0, 0)

#define MFMA16(a, b, c) __builtin_amdgcn_mfma_f32_16x16x32_f16((a), (b), (c), 0, 0, 0)
#define BAR() __builtin_amdgcn_s_barrier()
#define PRIO1() __builtin_amdgcn_s_setprio(1)
#define PRIO0() __builtin_amdgcn_s_setprio(0)
#define WAIT_LGKM(n) asm volatile("s_waitcnt lgkmcnt(" #n ")" ::: "memory")
#define WAIT_VM(n)   asm volatile("s_waitcnt vmcnt(" #n ")" ::: "memory")

// ---------------------------------------------------------------------------
// fp16 1-term GEMM (C = A*B^T), 256xBNT tile, 8 waves, never-drain counted
// pipeline. K-tile 64 (k-half planes).  FINAL (r23 config, verified best):
//   BNT=256: FINE 4-phase split. Phases F0..F3 = 16-MFMA regions {p0·mi0-3,
//     p0·mi4-7, p1·mi0-3, p1·mi4-7}; reads issued ONE phase ahead; one stage
//     unit per phase {F0:A0', F1:B0', F2:A1', F3:B1'}; lgkm 4/8/4/8 (exact
//     FIFO); vm(4)@F1 seals p1(t), vm(4)@F3 seals p0(t+1); 2 barriers/tile;
//     vm(0)/lgkm(0) only prologue + last tile.
//   BNT=128 (TRANSV V-proj): r19 2-phase loop verbatim.
// LDS planes [rows][64B], 4-slot XOR swizzle (slot = chunk ^ ((row>>1)&3)),
// both sides, 0-conflict (r10-verified). XCD-bijective block swizzle (m204).
// Epilogues: CM_F32/CM_F16 scalar; CM_TRANSV LDS-transposed coalesced.
// Tested and rejected: coarse phases (42% util), 2-bar merged lead (r21),
// LDS-staged F32/F16 epilogue (r18), BK=32 2-blocks/CU (r24), 32x32 MFMA
// (r11), macro-unroll running pointers (r12 spill).
// ---------------------------------------------------------------------------
template <int CMODE, int BNT>
__global__ __launch_bounds__(512, 1) void bgemm256(
    const _Float16* __restrict__ Ah_, long sAz,
    const _Float16* __restrict__ Bh_, long sBz,
    int lda, int ldb,
    void* __restrict__ C1, int ldc, long sCz,
    const float* __restrict__ bias, int K)
{
    extern __shared__ char smem[];
    constexpr int NW_N  = BNT / 64;          // 4 or 2
    constexpr int NW_M  = 8 / NW_N;          // 2 or 4
    constexpr int WM    = 256 / NW_M;        // 128 or 64
    constexpr int MI    = WM / 16;           // 8 or 4
    constexpr int APLANE = 16384;            // 256 rows x 64 B
    constexpr int BPLANE = BNT * 64;         // 16 KB or 8 KB
    constexpr int BOFF   = 2 * APLANE;
    constexpr int BUFSZ  = 2 * APLANE + 2 * BPLANE;

    // ---- XCD-aware bijective block swizzle (T1, m204) ----
    int bx, by, bz;
    {
        const int gx = gridDim.x, gy = gridDim.y;
        const int nwg = gx * gy * gridDim.z;
        const int wg = blockIdx.x + gx * (blockIdx.y + gy * blockIdx.z);
        const int q = nwg >> 3, r = nwg & 7;
        const int xcd = wg & 7, i = wg >> 3;
        const int nid = (xcd < r) ? xcd * (q + 1) + i
                                  : r * (q + 1) + (xcd - r) * q + i;
        bx = nid % gx;
        const int tmp = nid / gx;
        by = tmp % gy;
        bz = tmp / gy;
    }

    const int t = threadIdx.x;
    const int z = bz;
    const int m0 = by * 256;
    const int n0 = bx * BNT;
    const int lane = t & 63, wid = t >> 6;
    const int wr = wid / NW_N, wc = wid % NW_N;
    const int fr = lane & 15, fq = lane >> 4;
    const int lrow = lane >> 2, lslot = lane & 3;

    const _Float16* Ahz = Ah_ + (long)z * sAz;
    const _Float16* Bhz = Bh_ + (long)z * sBz;

    auto stA = [&](int tile, int p) {
        char* lbase = smem + (tile & 1) * BUFSZ + p * APLANE;
#pragma unroll
        for (int i = 0; i < 2; ++i) {
            const int row = wid * 32 + i * 16 + lrow;
            const int chunk = lslot ^ ((row >> 1) & 3);
            const long kk = (long)tile * 64 + p * 32 + chunk * 8;
            GLD16(Ahz + (long)(m0 + row) * lda + kk,
                  lbase + (wid * 32 + i * 16) * 64);
        }
    };
    auto stB = [&](int tile, int p) {
        char* lbase = smem + (tile & 1) * BUFSZ + BOFF + p * BPLANE;
        if constexpr (BNT == 256) {
#pragma unroll
            for (int i = 0; i < 2; ++i) {
                const int row = wid * 32 + i * 16 + lrow;
                const int chunk = lslot ^ ((row >> 1) & 3);
                const long kk = (long)tile * 64 + p * 32 + chunk * 8;
                GLD16(Bhz + (long)(n0 + row) * ldb + kk,
                      lbase + (wid * 32 + i * 16) * 64);
            }
        } else {
            const int row = wid * 16 + lrow;
            const int chunk = lslot ^ ((row >> 1) & 3);
            const long kk = (long)tile * 64 + p * 32 + chunk * 8;
            GLD16(Bhz + (long)(n0 + row) * ldb + kk, lbase + (wid * 16) * 64);
        }
    };
    auto rdA = [&](int buf, int p, int mi) -> f16x8 {
        const int row = wr * WM + mi * 16 + fr;
        const int slot = fq ^ ((row >> 1) & 3);
        return *(const f16x8*)(smem + buf * BUFSZ + p * APLANE +
                               row * 64 + slot * 16);
    };
    auto rdB = [&](int buf, int p, int ni) -> f16x8 {
        const int row = wc * 64 + ni * 16 + fr;
        const int slot = fq ^ ((row >> 1) & 3);
        return *(const f16x8*)(smem + buf * BUFSZ + BOFF + p * BPLANE +
                               row * 64 + slot * 16);
    };

    f32x4 acc[MI][4] = {};
    const int ktiles = K / 64;

    if constexpr (BNT == 256) {
        // ---- fine 4-phase loop (r23, verified best), MI == 8 ----
        f16x8 b0[4], b1[4], a0[8], a1[8];
        stA(0, 0); stB(0, 0); stA(0, 1); stB(0, 1);
        WAIT_VM(0);
        BAR();
#pragma unroll
        for (int ni = 0; ni < 4; ++ni) b0[ni] = rdB(0, 0, ni);
#pragma unroll
        for (int mi = 0; mi < 4; ++mi) a0[mi] = rdA(0, 0, mi);

        for (int tt = 0; tt < ktiles; ++tt) {
            const int buf = tt & 1;
            const bool pf = (tt + 1 < ktiles);
            // ---- F0: stage A0(t+1); issue a0[4-7]; MFMA p0 mi0-3 ----
            if (pf) stA(tt + 1, 0);
#pragma unroll
            for (int mi = 0; mi < 4; ++mi) a0[4 + mi] = rdA(buf, 0, 4 + mi);
            WAIT_LGKM(4);                  // b0, a0[0-3] landed (a0hi in flight)
            PRIO1();
#pragma unroll
            for (int mi = 0; mi < 4; ++mi)
#pragma unroll
                for (int ni = 0; ni < 4; ++ni)
                    acc[mi][ni] = MFMA16(a0[mi], b0[ni], acc[mi][ni]);
            PRIO0();
            // ---- F1: stage B0(t+1); seal p1(t); issue b1,a1[0-3]; MFMA p0 mi4-7 ----
            if (pf) { stB(tt + 1, 0); WAIT_VM(4); }   // retires A1,B1(t)
            else    { WAIT_VM(0); }
            BAR();                                    // p1(t) sealed block-wide
#pragma unroll
            for (int ni = 0; ni < 4; ++ni) b1[ni] = rdB(buf, 1, ni);
#pragma unroll
            for (int mi = 0; mi < 4; ++mi) a1[mi] = rdA(buf, 1, mi);
            WAIT_LGKM(8);                  // a0[4-7] landed (b1,a1lo in flight)
            PRIO1();
#pragma unroll
            for (int mi = 0; mi < 4; ++mi)
#pragma unroll
                for (int ni = 0; ni < 4; ++ni)
                    acc[4 + mi][ni] = MFMA16(a0[4 + mi], b0[ni], acc[4 + mi][ni]);
            PRIO0();
            // ---- F2: stage A1(t+1); issue a1[4-7]; MFMA p1 mi0-3 ----
            if (pf) stA(tt + 1, 1);
#pragma unroll
            for (int mi = 0; mi < 4; ++mi) a1[4 + mi] = rdA(buf, 1, 4 + mi);
            WAIT_LGKM(4);                  // b1, a1[0-3] landed (a1hi in flight)
            PRIO1();
#pragma unroll
            for (int mi = 0; mi < 4; ++mi)
#pragma unroll
                for (int ni = 0; ni < 4; ++ni)
                    acc[mi][ni] = MFMA16(a1[mi], b1[ni], acc[mi][ni]);
            PRIO0();
            // ---- F3: stage B1(t+1); seal p0(t+1); tail reads; MFMA p1 mi4-7 ----
            if (pf) { stB(tt + 1, 1); WAIT_VM(4); }   // retires A0,B0(t+1)
            else    { WAIT_VM(0); }
            BAR();                                    // p0(t+1) sealed block-wide
            if (pf) {
                const int nb = buf ^ 1;
#pragma unroll
                for (int ni = 0; ni < 4; ++ni) b0[ni] = rdB(nb, 0, ni);
#pragma unroll
                for (int mi = 0; mi < 4; ++mi) a0[mi] = rdA(nb, 0, mi);
                WAIT_LGKM(8);              // a1[4-7] landed (tail in flight)
            } else {
                WAIT_LGKM(0);
            }
            PRIO1();
#pragma unroll
            for (int mi = 0; mi < 4; ++mi)
#pragma unroll
                for (int ni = 0; ni < 4; ++ni)
                    acc[4 + mi][ni] = MFMA16(a1[4 + mi], b1[ni], acc[4 + mi][ni]);
            PRIO0();
        }
    } else {
        // ---- BNT=128: r19 2-phase loop verbatim (verified) ----
        f16x8 b0[4], b1[4], a0[MI], a1[MI];
        auto mb = [&](f16x8 (&A)[MI], f16x8 (&B)[4]) {
#pragma unroll
            for (int mi = 0; mi < MI; ++mi)
#pragma unroll
                for (int ni = 0; ni < 4; ++ni)
                    acc[mi][ni] = MFMA16(A[mi], B[ni], acc[mi][ni]);
        };
        stA(0, 0); stB(0, 0); stA(0, 1); stB(0, 1);
        WAIT_VM(0);
        BAR();
#pragma unroll
        for (int ni = 0; ni < 4; ++ni) b0[ni] = rdB(0, 0, ni);
#pragma unroll
        for (int mi = 0; mi < MI; ++mi) a0[mi] = rdA(0, 0, mi);

        for (int tt = 0; tt < ktiles; ++tt) {
            const int buf = tt & 1;
            const bool pf = (tt + 1 < ktiles);
            if (pf) { stA(tt + 1, 0); stB(tt + 1, 0); WAIT_VM(3); }
            else    { WAIT_VM(0); }
            BAR();
#pragma unroll
            for (int ni = 0; ni < 4; ++ni) b1[ni] = rdB(buf, 1, ni);
#pragma unroll
            for (int mi = 0; mi < MI; ++mi) a1[mi] = rdA(buf, 1, mi);
            WAIT_LGKM(8);
            PRIO1(); mb(a0, b0); PRIO0();
            BAR();
            if (pf) { stA(tt + 1, 1); stB(tt + 1, 1); WAIT_VM(3); }
            WAIT_LGKM(0);
            BAR();
            PRIO1(); mb(a1, b1); PRIO0();
            if (pf) {
                const int nb = buf ^ 1;
#pragma unroll
                for (int ni = 0; ni < 4; ++ni) b0[ni] = rdB(nb, 0, ni);
#pragma unroll
                for (int mi = 0; mi < MI; ++mi) a0[mi] = rdA(nb, 0, mi);
            }
        }
    }

    // ---------------- epilogue ----------------
    if constexpr (CMODE == CM_TRANSV) {
        // BNT=128 only. LDS transpose: Tt[128 d][272 f16] (544-B stride).
        constexpr int LDT = 544;
#pragma unroll
        for (int mi = 0; mi < MI; ++mi) {
            const int row0 = wr * WM + mi * 16 + fq * 4;   // 0..255, mult of 4
#pragma unroll
            for (int ni = 0; ni < 4; ++ni) {
                const int colp = wc * 64 + ni * 16 + fr;    // 0..127
                const float bv = bias[n0 + colp];
                f16x4 h;
#pragma unroll
                for (int j = 0; j < 4; ++j) h[j] = (_Float16)(acc[mi][ni][j] + bv);
                *(f16x4*)(smem + colp * LDT + row0 * 2) = h;
            }
        }
        BAR();
        const int b_ = m0 >> 11;
        const int sbase = m0 & (S - 1);
        const int l31 = lane & 31, lh = lane >> 5;
        _Float16* Vp = (_Float16*)C1;
#pragma unroll
        for (int it = 0; it < 8; ++it) {
            const int dd = wid * 16 + it * 2 + lh;
            const f16x8 v = *(const f16x8*)(smem + dd * LDT + l31 * 16);
            *(f16x8*)(Vp + ((long)(b_ * D + n0 + dd)) * S + sbase + l31 * 8) = v;
        }
    } else {
#pragma unroll
        for (int mi = 0; mi < MI; ++mi) {
            const int rbase = m0 + wr * WM + mi * 16 + fq * 4;
#pragma unroll
            for (int ni = 0; ni < 4; ++ni) {
                const int col = n0 + wc * 64 + ni * 16 + fr;
                f32x4 a = acc[mi][ni];
                if (CMODE != CM_F32) {
                    const float bv = bias[col];
#pragma unroll
                    for (int j = 0; j < 4; ++j) a[j] += bv;
                }
                if (CMODE == CM_F32) {
                    float* C = (float*)C1 + (long)z * sCz;
#pragma unroll
                    for (int j = 0; j < 4; ++j)
                        C[(long)(rbase + j) * ldc + col] = a[j];
                } else {  // CM_F16
                    _Float16* Ch = (_Float16*)C1;
#pragma unroll
                    for (int j = 0; j < 4; ++j)
                        Ch[(long)(rbase + j) * ldc + col] = (_Float16)a[j];
                }
            }
        }
    }
}

// ---------------------------------------------------------------------------
// X -> single fp16 plane.
__global__ __launch_bounds__(256) void xsplit(
    const float* __restrict__ X, _Float16* __restrict__ Xh)
{
    const long i = ((long)blockIdx.x * 256 + threadIdx.x) * 8;
    f32x4 v0 = *(const f32x4*)(X + i);
    f32x4 v1 = *(const f32x4*)(X + i + 4);
    f16x8 h;
#pragma unroll
    for (int j = 0; j < 4; ++j) { h[j] = (_Float16)v0[j]; h[4 + j] = (_Float16)v1[j]; }
    *(f16x8*)(Xh + i) = h;
}

// ---------------------------------------------------------------------------
// Transpose 1024x1024 W -> single f16 plane (1-term projections).
__global__ void wsplit(const float* __restrict__ W0, const float* __restrict__ W1,
                       const float* __restrict__ W2, _Float16* __restrict__ Th)
{
    const float* W = blockIdx.z == 0 ? W0 : (blockIdx.z == 1 ? W1 : W2);
    _Float16* th = Th + (long)blockIdx.z * 1024 * 1024;
    __shared__ float tile[32][33];
    const int bx = blockIdx.x * 32, by = blockIdx.y * 32;
    const int tx = threadIdx.x, ty = threadIdx.y;
#pragma unroll
    for (int i = ty; i < 32; i += 8) tile[i][tx] = W[(long)(by + i) * 1024 + bx + tx];
    __syncthreads();
#pragma unroll
    for (int i = ty; i < 32; i += 8)
        th[(long)(bx + i) * 1024 + by + tx] = (_Float16)tile[tx][i];
}

// ---------------------------------------------------------------------------
// Fused row softmax: f32 score row -> P = exp(s-m)/l as fp16, in-place.
__global__ __launch_bounds__(256) void pconv(float* __restrict__ Sb)
{
    const long row = blockIdx.x;
    float* p = Sb + row * (long)S;
    const int t = threadIdx.x;

    f32x4 x0 = *(const f32x4*)(p + t * 8);
    f32x4 x1 = *(const f32x4*)(p + t * 8 + 4);

    float m = -3.4e38f;
#pragma unroll
    for (int j = 0; j < 4; ++j) m = fmaxf(m, fmaxf(x0[j], x1[j]));
#pragma unroll
    for (int o = 32; o >= 1; o >>= 1) m = fmaxf(m, __shfl_xor(m, o));

    __shared__ float wm[4], wsum[4];
    const int wid = t >> 6, lane = t & 63;
    if (lane == 0) wm[wid] = m;
    __syncthreads();
    m = fmaxf(fmaxf(wm[0], wm[1]), fmaxf(wm[2], wm[3]));

    float e[8], ssum = 0.f;
#pragma unroll
    for (int j = 0; j < 4; ++j) {
        e[j]     = exp2f((x0[j] - m) * LOG2E);
        e[4 + j] = exp2f((x1[j] - m) * LOG2E);
        ssum += e[j] + e[4 + j];
    }
#pragma unroll
    for (int o = 32; o >= 1; o >>= 1) ssum += __shfl_xor(ssum, o);
    if (lane == 0) wsum[wid] = ssum;
    __syncthreads();
    const float invl = 1.0f / (wsum[0] + wsum[1] + wsum[2] + wsum[3]);

    f16x8 outv;
#pragma unroll
    for (int j = 0; j < 8; ++j) outv[j] = (_Float16)(e[j] * invl);
    *(f16x8*)((_Float16*)p + t * 8) = outv;
}

// ---------------------------------------------------------------------------
extern "C" void kernel_launch(void* const* d_in, const int* in_sizes, int n_in,
                              void* d_out, int out_size, void* d_ws, size_t ws_size,
                              hipStream_t stream)
{
    const float* X  = (const float*)d_in[0];
    const float* Wq = (const float*)d_in[1];
    const float* bq = (const float*)d_in[2];
    const float* Wk = (const float*)d_in[3];
    const float* bk = (const float*)d_in[4];
    const float* Wv = (const float*)d_in[5];
    const float* bv = (const float*)d_in[6];
    float* out = (float*)d_out;
    char* ws = (char*)d_ws;
    const size_t MB = 1u << 20;

    // layout (230 MB): [0,6) Wh[3] f16  [6,38) Qh f16  [38,70) Kh f16
    // [70,102) Vt f16  [102,230) Sb f32 [8][S][S] (P f16 in-place)
    // Xh (32 MB f16) aliases Sb's first part [102,134) — dead before scores.
    _Float16* Wh = (_Float16*)ws;
    _Float16* Qh = (_Float16*)(ws + 6 * MB);
    _Float16* Kh = (_Float16*)(ws + 38 * MB);
    _Float16* Vt = (_Float16*)(ws + 70 * MB);
    float*    Sb = (float*)(ws + 102 * MB);
    _Float16* Xh = (_Float16*)(ws + 102 * MB);

    const int LDS_256 = 131072;   // 2 bufs x (2x16K A + 2x16K B)
    const int LDS_128 = 98304;    // 2 bufs x (2x16K A + 2x8K B)
    (void)hipFuncSetAttribute(reinterpret_cast<const void*>(&bgemm256<CM_F16, 256>),
                        hipFuncAttributeMaxDynamicSharedMemorySize, LDS_256);
    (void)hipFuncSetAttribute(reinterpret_cast<const void*>(&bgemm256<CM_F32, 256>),
                        hipFuncAttributeMaxDynamicSharedMemorySize, LDS_256);
    (void)hipFuncSetAttribute(reinterpret_cast<const void*>(&bgemm256<CM_TRANSV, 128>),
                        hipFuncAttributeMaxDynamicSharedMemorySize, LDS_128);

    // 1) convert X -> f16 single plane; W -> f16 single plane (transposed)
    xsplit<<<dim3(8192), 256, 0, stream>>>(X, Xh);
    wsplit<<<dim3(32, 32, 3), dim3(32, 8), 0, stream>>>(Wq, Wk, Wv, Wh);

    // 2) projections: 1-term fp16 (Xh * Wh); Q,K single f16; V -> Vt f16.
    const long MW = 1024 * 1024;
    bgemm256<CM_F16, 256><<<dim3(D / 256, 64, 1), 512, LDS_256, stream>>>(
        Xh, 0, Wh, 0, D, D, Qh, D, 0, bq, D);
    bgemm256<CM_F16, 256><<<dim3(D / 256, 64, 1), 512, LDS_256, stream>>>(
        Xh, 0, Wh + MW, 0, D, D, Kh, D, 0, bk, D);
    bgemm256<CM_TRANSV, 128><<<dim3(D / 128, 64, 1), 512, LDS_128, stream>>>(
        Xh, 0, Wh + 2 * MW, 0, D, D, Vt, 0, 0, bv, D);

    // 3) single pass, all 8 batches: scores -> softmax->f16 P -> PV
    bgemm256<CM_F32, 256><<<dim3(S / 256, S / 256, NB), 512, LDS_256, stream>>>(
        Qh, (long)S * D, Kh, (long)S * D,
        D, D, Sb, S, (long)S * S, nullptr, D);
    pconv<<<dim3(NB * S), 256, 0, stream>>>(Sb);
    // PV: A = f16 P rows embedded in f32 buffer (lda = 2S f16 elements)
    bgemm256<CM_F32, 256><<<dim3(D / 256, S / 256, NB), 512, LDS_256, stream>>>(
        (const _Float16*)Sb, 2L * S * S, Vt, (long)D * S,
        2 * S, S, out, D, (long)S * D, nullptr, S);
}